// Round 14
// baseline (383.177 us; speedup 1.0000x reference)
//
#include <hip/hip_runtime.h>
#include <stdint.h>

typedef float f32x4 __attribute__((ext_vector_type(4)));
typedef short s16x8 __attribute__((ext_vector_type(8)));

#define EDIM 64
#define HID 128
#define NG 128
#define NC 10
#define WPB 8             // waves per block
#define TPB (WPB * 64)    // 512 threads
#define NBLK 512          // edge kernel blocks (2/CU exactly)
#define NWAVES (NBLK * WPB)
#define NEG_INF -3.402823466e38f

static __device__ __forceinline__ unsigned short f2bf(float x) {
  unsigned int u = __float_as_uint(x);
  u += 0x7FFFu + ((u >> 16) & 1u);   // round-to-nearest-even
  return (unsigned short)(u >> 16);
}
static __device__ __forceinline__ unsigned int cvtpk(float lo, float hi) {
  unsigned int r;
  asm("v_cvt_pk_bf16_f32 %0, %1, %2" : "=v"(r) : "v"(lo), "v"(hi));
  return r;
}
static __device__ __forceinline__ s16x8 mk8(unsigned int a, unsigned int b,
                                            unsigned int c, unsigned int d) {
  union { unsigned int u[4]; s16x8 v; } x;
  x.u[0] = a; x.u[1] = b; x.u[2] = c; x.u[3] = d;
  return x.v;
}
// K-position permutation: p[6:5]|p[4:3]|p[2:0] -> u = p[6:5]|p[2]|p[4:3]|p[1:0]
static __device__ __forceinline__ int sigma(int p) {
  return (p & 0x60) | ((p & 4) << 2) | ((p >> 1) & 0xC) | (p & 3);
}

// ---------------- setup1: pack weights + zero cnt + zero sums + h_self ----------------
__global__ void setup1_kernel(const float* __restrict__ W1, const float* __restrict__ W2,
                              const float* __restrict__ W3, const float* __restrict__ b1,
                              const float* __restrict__ b2, const float* __restrict__ b3,
                              unsigned short* __restrict__ wt1, unsigned short* __restrict__ wt2,
                              unsigned short* __restrict__ wt3, unsigned int* __restrict__ cnt,
                              float* __restrict__ pool0, float* __restrict__ hself_f,
                              int N, int zbc, int zbs, int SUMN) {
  __shared__ float s1[HID], s2[HID];
  const int b = blockIdx.x, t = threadIdx.x;
  if (b < 160) {                               // pack 40960 elements
    int gid = b * 256 + t;
    if (gid < 8192) {                          // W1: K=64 natural, N=128
      int k = gid >> 7, n = gid & 127;
      int off = (n * 128 + k * 2) ^ ((n & 7) << 4);
      *(unsigned short*)((char*)wt1 + off) = f2bf(W1[k * 128 + n]);
    } else if (gid < 24576) {                  // W2: K=128 sigma-permuted
      int idx = gid - 8192; int kp = idx >> 7, n = idx & 127;
      int off = (n * 256 + kp * 2) ^ ((n & 7) << 4);
      *(unsigned short*)((char*)wt2 + off) = f2bf(W2[sigma(kp) * 128 + n]);
    } else {                                   // W3: K=128 sigma-permuted
      int idx = gid - 24576; int kp = idx >> 7, n = idx & 127;
      int off = (n * 256 + kp * 2) ^ ((n & 7) << 4);
      *(unsigned short*)((char*)wt3 + off) = f2bf(W3[sigma(kp) * 128 + n]);
    }
  } else if (b < 160 + zbc) {                  // zero histogram, uint4
    int i4 = ((b - 160) * 256 + t) * 4;
    if (i4 + 3 < N) {
      uint4 z; z.x = z.y = z.z = z.w = 0u;
      *(uint4*)(cnt + i4) = z;
    } else {
      for (int j = 0; j < 4; ++j) if (i4 + j < N) cnt[i4 + j] = 0u;
    }
  } else if (b < 160 + zbc + zbs) {            // zero pool sums/counts, float4
    int i4 = ((b - 160 - zbc) * 256 + t) * 4;
    if (i4 + 3 < SUMN) {
      float4 z; z.x = z.y = z.z = z.w = 0.f;
      *(float4*)(pool0 + i4) = z;
    } else {
      for (int j = 0; j < 4; ++j) if (i4 + j < SUMN) pool0[i4 + j] = 0.f;
    }
  } else {                                     // h_self = MLP(0), f32 exact
    float h1 = 0.f, h2 = 0.f;
    if (t < HID) { h1 = b1[t]; h1 = h1 > 0.f ? h1 : 0.f; s1[t] = h1; }
    __syncthreads();
    if (t < HID) {
      h2 = b2[t];
      for (int k = 0; k < HID; ++k) h2 += s1[k] * W2[k * HID + t];
      h2 = h2 > 0.f ? h2 : 0.f; s2[t] = h2;
    }
    __syncthreads();
    if (t < HID) {
      float h3 = b3[t];
      for (int k = 0; k < HID; ++k) h3 += s2[k] * W3[k * HID + t];
      hself_f[t] = h3;
    }
  }
}

// ---------------- histogram (int4) + zero the block-done counter ----------------
__global__ void hist_kernel(const int* __restrict__ dst, unsigned int* __restrict__ cnt,
                            unsigned int* __restrict__ done, int E) {
  if (blockIdx.x == 0 && threadIdx.x == 0) *done = 0u;
  int i4 = (blockIdx.x * 256 + threadIdx.x) * 4;
  if (i4 + 3 < E) {
    int4 d4 = *(const int4*)(dst + i4);
    atomicAdd(&cnt[d4.x], 1u); atomicAdd(&cnt[d4.y], 1u);
    atomicAdd(&cnt[d4.z], 1u); atomicAdd(&cnt[d4.w], 1u);
  } else {
    for (int j = 0; j < 4; ++j) if (i4 + j < E) atomicAdd(&cnt[dst[i4 + j]], 1u);
  }
}

// ---------------- scan phase 1: intra-block exclusive + raw block totals ----------------
__global__ void scan1_kernel(unsigned int* __restrict__ cnt, unsigned int* __restrict__ part,
                             int N) {
  __shared__ unsigned int sh[256];
  const int t = threadIdx.x;
  const int base = blockIdx.x * 1024 + t * 4;
  unsigned int v[4]; unsigned int s = 0;
  #pragma unroll
  for (int j = 0; j < 4; ++j) { v[j] = (base + j < N) ? cnt[base + j] : 0u; s += v[j]; }
  sh[t] = s; __syncthreads();
  for (int off = 1; off < 256; off <<= 1) {
    unsigned int x = (t >= off) ? sh[t - off] : 0u;
    __syncthreads();
    sh[t] += x;
    __syncthreads();
  }
  if (t == 255) part[blockIdx.x] = sh[255];
  unsigned int excl = (t == 0) ? 0u : sh[t - 1];
  #pragma unroll
  for (int j = 0; j < 4; ++j) {
    if (base + j < N) { unsigned int old = v[j]; cnt[base + j] = excl; excl += old; }
  }
}

// ---------------- scan phases 2+3 merged ----------------
__global__ void scan23_kernel(unsigned int* __restrict__ cnt, const unsigned int* __restrict__ part,
                              unsigned int* __restrict__ cursor, int N) {
  __shared__ unsigned int red[256];
  const int t = threadIdx.x;
  const int chunk = blockIdx.x >> 2;             // 4 blocks of 256 per 1024-chunk
  red[t] = (t < chunk) ? part[t] : 0u;
  __syncthreads();
  for (int off = 128; off > 0; off >>= 1) {
    if (t < off) red[t] += red[t + off];
    __syncthreads();
  }
  const unsigned int offv = red[0];
  int i = blockIdx.x * 256 + t;
  if (i < N) {
    unsigned int v = cnt[i] + offv;
    cnt[i] = v;          // row_ptr (preserved)
    cursor[i] = v;       // mutable copy for fill
  }
}

// ---------------- fill (int4 -> int2 epd) + per-wave node-aligned ranges (+wnode) ----------------
__global__ void fillrange_kernel(const int* __restrict__ dst, unsigned int* __restrict__ cursor,
                                 int2* __restrict__ epd, const unsigned int* __restrict__ row_ptr,
                                 unsigned int* __restrict__ wstart, unsigned int* __restrict__ wnode,
                                 int N, int E, int W, int fillB) {
  const int b = blockIdx.x, t = threadIdx.x;
  if (b < fillB) {
    int i4 = (b * 256 + t) * 4;
    if (i4 + 3 < E) {
      int4 d4 = *(const int4*)(dst + i4);
      unsigned int p0 = atomicAdd(&cursor[d4.x], 1u); epd[p0] = make_int2(i4 + 0, d4.x);
      unsigned int p1 = atomicAdd(&cursor[d4.y], 1u); epd[p1] = make_int2(i4 + 1, d4.y);
      unsigned int p2 = atomicAdd(&cursor[d4.z], 1u); epd[p2] = make_int2(i4 + 2, d4.z);
      unsigned int p3 = atomicAdd(&cursor[d4.w], 1u); epd[p3] = make_int2(i4 + 3, d4.w);
    } else {
      for (int j = 0; j < 4; ++j)
        if (i4 + j < E) {
          int d = dst[i4 + j];
          unsigned int p = atomicAdd(&cursor[d], 1u);
          epd[p] = make_int2(i4 + j, d);
        }
    }
  } else {
    int w = (b - fillB) * 256 + t;
    if (w > W) return;
    unsigned int target = (unsigned int)(((unsigned long long)w * (unsigned long long)E) /
                                         (unsigned long long)W);
    int lo = 0, hi = N;
    while (lo < hi) {
      int mid = (lo + hi) >> 1;
      if (row_ptr[mid] >= target) hi = mid; else lo = mid + 1;
    }
    wnode[w] = (unsigned int)lo;
    wstart[w] = (lo < N) ? row_ptr[lo] : (unsigned int)E;
  }
}

// ---------------- fused edge MLP + exclusive segmented-max + POOL TAIL + LAST-BLOCK CLS ----------------
__global__ __launch_bounds__(TPB, 2) void edge_kernel(
    const float* __restrict__ edge_attr, const int2* __restrict__ epd,
    const float* __restrict__ hself_f,
    const unsigned short* __restrict__ wt1, const unsigned short* __restrict__ wt2,
    const unsigned short* __restrict__ wt3, float* __restrict__ node_f,
    const unsigned int* __restrict__ wstart, const unsigned int* __restrict__ wnode,
    const int* __restrict__ batch, const unsigned int* __restrict__ row_ptr,
    float* __restrict__ sums, float* __restrict__ counts,
    const float* __restrict__ Wc1, const float* __restrict__ bc1,
    const float* __restrict__ Wc2, const float* __restrict__ bc2,
    float* __restrict__ out, unsigned int* __restrict__ done, int N, int E) {
  __shared__ __align__(16) unsigned char smem[81920];   // 80 KB (2 blocks/CU)
  unsigned short* Wb1 = (unsigned short*)smem;           // 16 KB
  unsigned short* Wb2 = (unsigned short*)(smem + 16384); // 32 KB
  unsigned short* Wb3 = (unsigned short*)(smem + 49152); // 32 KB

  const int tid = threadIdx.x;
  { // stage all three weight matrices once
    const uint4* s1 = (const uint4*)wt1; uint4* d1 = (uint4*)Wb1;
    #pragma unroll
    for (int i = 0; i < 2; ++i) d1[tid + i * TPB] = s1[tid + i * TPB];
    const uint4* s2 = (const uint4*)wt2; uint4* d2 = (uint4*)Wb2;
    #pragma unroll
    for (int i = 0; i < 4; ++i) d2[tid + i * TPB] = s2[tid + i * TPB];
    const uint4* s3 = (const uint4*)wt3; uint4* d3 = (uint4*)Wb3;
    #pragma unroll
    for (int i = 0; i < 4; ++i) d3[tid + i * TPB] = s3[tid + i * TPB];
  }
  __syncthreads();

  const int w = tid >> 6;
  const int l = tid & 63;
  const int hi = l >> 4;         // lane quarter 0..3
  const int lm = l & 15;         // 0..15

  const int gw = blockIdx.x * WPB + w;
  const int s = (int)wstart[gw];
  const int e = (int)wstart[gw + 1];

  if (s < e) {
    float hs[8];
    #pragma unroll
    for (int nf = 0; nf < 8; ++nf) hs[nf] = hself_f[nf * 16 + lm];

    int pd = -1;   // previous subtile's last dst (wave-uniform)

    // ---- prologue: gather+convert tile s; peN = perm ids for s+32 ----
    s16x8 a1[2][2];
    int peN[2];
    {
      int pe[2];
      #pragma unroll
      for (int m = 0; m < 2; ++m) {
        int er = s + m * 16 + lm; if (er >= e) er = e - 1;
        pe[m] = epd[er].x;
      }
      f32x4 raw[8];
      #pragma unroll
      for (int m = 0; m < 2; ++m) {
        const float* ap = edge_attr + (size_t)pe[m] * EDIM + hi * 8;
        #pragma unroll
        for (int kf = 0; kf < 2; ++kf) {
          raw[m * 4 + kf * 2 + 0] = __builtin_nontemporal_load((const f32x4*)(ap + kf * 32));
          raw[m * 4 + kf * 2 + 1] = __builtin_nontemporal_load((const f32x4*)(ap + kf * 32 + 4));
        }
      }
      #pragma unroll
      for (int m = 0; m < 2; ++m) {
        int er = s + 32 + m * 16 + lm; if (er >= e) er = e - 1;
        peN[m] = epd[er].x;
      }
      #pragma unroll
      for (int m = 0; m < 2; ++m)
        #pragma unroll
        for (int kf = 0; kf < 2; ++kf) {
          f32x4 x0 = raw[m * 4 + kf * 2 + 0];
          f32x4 x1 = raw[m * 4 + kf * 2 + 1];
          a1[m][kf] = mk8(cvtpk(x0[0], x0[1]), cvtpk(x0[2], x0[3]),
                          cvtpk(x1[0], x1[1]), cvtpk(x1[2], x1[3]));
        }
    }

    for (int t = s; t < e; t += 32) {
      f32x4 acc[2][8];
      #pragma unroll
      for (int m = 0; m < 2; ++m)
        #pragma unroll
        for (int nf = 0; nf < 8; ++nf) acc[m][nf] = (f32x4){0.f, 0.f, 0.f, 0.f};

      // ---- layer 1 (transposed) ----
      __builtin_amdgcn_s_setprio(1);
      #pragma unroll
      for (int kf = 0; kf < 2; ++kf) {
        #pragma unroll
        for (int nf = 0; nf < 8; ++nf) {
          int n = nf * 16 + lm;
          int off = (n * 128 + kf * 64 + hi * 16) ^ ((n & 7) << 4);
          s16x8 wf = *(const s16x8*)((const char*)Wb1 + off);
          acc[0][nf] = __builtin_amdgcn_mfma_f32_16x16x32_bf16(wf, a1[0][kf], acc[0][nf], 0, 0, 0);
          acc[1][nf] = __builtin_amdgcn_mfma_f32_16x16x32_bf16(wf, a1[1][kf], acc[1][nf], 0, 0, 0);
        }
      }
      __builtin_amdgcn_s_setprio(0);

      // ---- issue NEXT tile gather m=0 ----
      f32x4 rawA[4];
      {
        const float* ap = edge_attr + (size_t)peN[0] * EDIM + hi * 8;
        rawA[0] = __builtin_nontemporal_load((const f32x4*)(ap));
        rawA[1] = __builtin_nontemporal_load((const f32x4*)(ap + 4));
        rawA[2] = __builtin_nontemporal_load((const f32x4*)(ap + 32));
        rawA[3] = __builtin_nontemporal_load((const f32x4*)(ap + 36));
      }

      // ---- boundary 1: relu + pack ----
      unsigned int pk1[2][8][2];
      #pragma unroll
      for (int m = 0; m < 2; ++m)
        #pragma unroll
        for (int nf = 0; nf < 8; ++nf) {
          float v0 = fmaxf(acc[m][nf][0], 0.f), v1 = fmaxf(acc[m][nf][1], 0.f);
          float v2 = fmaxf(acc[m][nf][2], 0.f), v3 = fmaxf(acc[m][nf][3], 0.f);
          pk1[m][nf][0] = cvtpk(v0, v1);
          pk1[m][nf][1] = cvtpk(v2, v3);
        }

      // ---- layer 2 (transposed) ----
      #pragma unroll
      for (int m = 0; m < 2; ++m)
        #pragma unroll
        for (int nf = 0; nf < 8; ++nf) acc[m][nf] = (f32x4){0.f, 0.f, 0.f, 0.f};
      __builtin_amdgcn_s_setprio(1);
      #pragma unroll
      for (int kf = 0; kf < 4; ++kf) {
        s16x8 b0 = mk8(pk1[0][2 * kf][0], pk1[0][2 * kf][1],
                       pk1[0][2 * kf + 1][0], pk1[0][2 * kf + 1][1]);
        s16x8 b1f = mk8(pk1[1][2 * kf][0], pk1[1][2 * kf][1],
                        pk1[1][2 * kf + 1][0], pk1[1][2 * kf + 1][1]);
        #pragma unroll
        for (int nf = 0; nf < 8; ++nf) {
          int n = nf * 16 + lm;
          int off = (n * 256 + kf * 64 + hi * 16) ^ ((n & 7) << 4);
          s16x8 wf = *(const s16x8*)((const char*)Wb2 + off);
          acc[0][nf] = __builtin_amdgcn_mfma_f32_16x16x32_bf16(wf, b0, acc[0][nf], 0, 0, 0);
          acc[1][nf] = __builtin_amdgcn_mfma_f32_16x16x32_bf16(wf, b1f, acc[1][nf], 0, 0, 0);
        }
      }
      __builtin_amdgcn_s_setprio(0);

      // ---- convert rawA -> next a1[0]; issue gather m=1 ----
      a1[0][0] = mk8(cvtpk(rawA[0][0], rawA[0][1]), cvtpk(rawA[0][2], rawA[0][3]),
                     cvtpk(rawA[1][0], rawA[1][1]), cvtpk(rawA[1][2], rawA[1][3]));
      a1[0][1] = mk8(cvtpk(rawA[2][0], rawA[2][1]), cvtpk(rawA[2][2], rawA[2][3]),
                     cvtpk(rawA[3][0], rawA[3][1]), cvtpk(rawA[3][2], rawA[3][3]));
      f32x4 rawB[4];
      {
        const float* ap = edge_attr + (size_t)peN[1] * EDIM + hi * 8;
        rawB[0] = __builtin_nontemporal_load((const f32x4*)(ap));
        rawB[1] = __builtin_nontemporal_load((const f32x4*)(ap + 4));
        rawB[2] = __builtin_nontemporal_load((const f32x4*)(ap + 32));
        rawB[3] = __builtin_nontemporal_load((const f32x4*)(ap + 36));
      }

      // ---- boundary 2: relu + pack ----
      unsigned int pk2[2][8][2];
      #pragma unroll
      for (int m = 0; m < 2; ++m)
        #pragma unroll
        for (int nf = 0; nf < 8; ++nf) {
          float v0 = fmaxf(acc[m][nf][0], 0.f), v1 = fmaxf(acc[m][nf][1], 0.f);
          float v2 = fmaxf(acc[m][nf][2], 0.f), v3 = fmaxf(acc[m][nf][3], 0.f);
          pk2[m][nf][0] = cvtpk(v0, v1);
          pk2[m][nf][1] = cvtpk(v2, v3);
        }

      // ---- layer 3 (normal) ----
      #pragma unroll
      for (int m = 0; m < 2; ++m)
        #pragma unroll
        for (int nf = 0; nf < 8; ++nf) acc[m][nf] = (f32x4){0.f, 0.f, 0.f, 0.f};
      __builtin_amdgcn_s_setprio(1);
      #pragma unroll
      for (int kf = 0; kf < 4; ++kf) {
        s16x8 af0 = mk8(pk2[0][2 * kf][0], pk2[0][2 * kf][1],
                        pk2[0][2 * kf + 1][0], pk2[0][2 * kf + 1][1]);
        s16x8 af1 = mk8(pk2[1][2 * kf][0], pk2[1][2 * kf][1],
                        pk2[1][2 * kf + 1][0], pk2[1][2 * kf + 1][1]);
        #pragma unroll
        for (int nf = 0; nf < 8; ++nf) {
          int n = nf * 16 + lm;
          int off = (n * 256 + kf * 64 + hi * 16) ^ ((n & 7) << 4);
          s16x8 wf = *(const s16x8*)((const char*)Wb3 + off);
          acc[0][nf] = __builtin_amdgcn_mfma_f32_16x16x32_bf16(af0, wf, acc[0][nf], 0, 0, 0);
          acc[1][nf] = __builtin_amdgcn_mfma_f32_16x16x32_bf16(af1, wf, acc[1][nf], 0, 0, 0);
        }
      }
      __builtin_amdgcn_s_setprio(0);

      // ---- convert rawB -> next a1[1]; prefetch perm ids for t+64 ----
      a1[1][0] = mk8(cvtpk(rawB[0][0], rawB[0][1]), cvtpk(rawB[0][2], rawB[0][3]),
                     cvtpk(rawB[1][0], rawB[1][1]), cvtpk(rawB[1][2], rawB[1][3]));
      a1[1][1] = mk8(cvtpk(rawB[2][0], rawB[2][1]), cvtpk(rawB[2][2], rawB[2][3]),
                     cvtpk(rawB[3][0], rawB[3][1]), cvtpk(rawB[3][2], rawB[3][3]));
      int peN2[2];
      #pragma unroll
      for (int m = 0; m < 2; ++m) {
        int er = t + 64 + m * 16 + lm; if (er >= e) er = e - 1;
        peN2[m] = epd[er].x;
      }

      // ---- epilogue: dst ids + exclusive segmented max (f32 stores) ----
      int dd[2][4];
      #pragma unroll
      for (int m = 0; m < 2; ++m)
        #pragma unroll
        for (int i = 0; i < 4; ++i) {
          int e2 = t + m * 16 + hi * 4 + i;
          dd[m][i] = (e2 < e) ? epd[e2].y : -1;
        }

      #pragma unroll
      for (int m = 0; m < 2; ++m) {
        const int d0 = dd[m][0], d1 = dd[m][1], d2 = dd[m][2], d3 = dd[m][3];
        const bool q01 = (d0 == d1), q12 = (d1 == d2), q23 = (d2 == d3);
        const int dt = d3, dh = d0;
        const int uni = (d0 == d3);
        const int dh1 = __shfl_down(dh, 16), dh2 = __shfl_down(dh, 32), dh3 = __shfl_down(dh, 48);
        const int un1 = __shfl_down(uni, 16), un2 = __shfl_down(uni, 32);
        const int dtprev = __shfl_up(dt, 16);
        const bool c1 = (hi < 3) && (dh1 == dt);
        const bool c2 = c1 && un1 && (dh2 == dh1);
        const bool c3 = c2 && un2 && (dh3 == dh2);
        const bool h0 = (hi == 0) || (dtprev != d0);
        const bool h1 = !q01, h2 = !q12, h3 = !q23;
        const int d_last = __shfl(d3, 48);

        const bool cont = (hi == 0) && (d0 >= 0) && (d0 == pd);
        float prevv[8];
        if (cont) {
          #pragma unroll
          for (int nf = 0; nf < 8; ++nf)
            prevv[nf] = node_f[(size_t)d0 * HID + nf * 16 + lm];
        }

        #pragma unroll
        for (int nf = 0; nf < 8; ++nf) {
          float v0 = acc[m][nf][0], v1 = acc[m][nf][1], v2 = acc[m][nf][2], v3 = acc[m][nf][3];
          float s3 = v3;
          float s2 = q23 ? fmaxf(v2, s3) : v2;
          float s1 = q12 ? fmaxf(v1, s2) : v1;
          float s0 = q01 ? fmaxf(v0, s1) : v0;
          float S1 = __shfl_down(s0, 16), S2 = __shfl_down(s0, 32), S3 = __shfl_down(s0, 48);
          float X = NEG_INF;
          X = c1 ? S1 : X;
          X = c2 ? fmaxf(X, S2) : X;
          X = c3 ? fmaxf(X, S3) : X;
          const float f0 = (d0 == dt) ? fmaxf(s0, X) : s0;
          const float f1 = (d1 == dt) ? fmaxf(s1, X) : s1;
          const float f2 = (d2 == dt) ? fmaxf(s2, X) : s2;
          const float f3 = fmaxf(s3, X);
          const int col = nf * 16 + lm;
          if (h0 && d0 >= 0) {
            float u = fmaxf(f0, hs[nf]);
            if (cont) u = fmaxf(u, prevv[nf]);
            node_f[(size_t)d0 * HID + col] = u;
          }
          if (h1 && d1 >= 0) node_f[(size_t)d1 * HID + col] = fmaxf(f1, hs[nf]);
          if (h2 && d2 >= 0) node_f[(size_t)d2 * HID + col] = fmaxf(f2, hs[nf]);
          if (h3 && d3 >= 0) node_f[(size_t)d3 * HID + col] = fmaxf(f3, hs[nf]);
        }
        pd = d_last;
      }

      peN[0] = peN2[0]; peN[1] = peN2[1];
    }
  }

  // ---- POOL TAIL: this wave exclusively owns nodes [wnode[gw], wnode[gw+1]) ----
  {
    int n0 = (int)wnode[gw];
    int n1 = (gw == NWAVES - 1) ? N : (int)wnode[gw + 1];
    if (n1 > N) n1 = N;
    if (n0 < n1) {
      const int c0 = l * 2;   // each lane accumulates 2 features
      const float hsa = hself_f[c0], hsb = hself_f[c0 + 1];
      float sum0 = 0.f, sum1 = 0.f;
      int segn = 0;
      int cur = batch[n0];
      for (int n = n0; n < n1; ++n) {
        int g = batch[n];
        if (g != cur) {
          atomicAdd(&sums[cur * HID + c0], sum0);
          atomicAdd(&sums[cur * HID + c0 + 1], sum1);
          if (l == 0) atomicAdd(&counts[cur], (float)segn);
          sum0 = sum1 = 0.f; segn = 0; cur = g;
        }
        unsigned int rs = row_ptr[n];
        unsigned int re = (n + 1 < N) ? row_ptr[n + 1] : (unsigned int)E;
        if (re > rs) {
          sum0 += node_f[(size_t)n * HID + c0];
          sum1 += node_f[(size_t)n * HID + c0 + 1];
        } else {
          sum0 += hsa; sum1 += hsb;
        }
        segn++;
      }
      atomicAdd(&sums[cur * HID + c0], sum0);
      atomicAdd(&sums[cur * HID + c0 + 1], sum1);
      if (l == 0) atomicAdd(&counts[cur], (float)segn);
    }
  }

  // ---- LAST-BLOCK CLASSIFIER (weights LDS is dead now) ----
  int* lastFlag = (int*)(smem + 81900);        // inside dead Wb3 region
  __syncthreads();                              // all waves done (atomics issued)
  if (tid == 0) {
    __threadfence();
    unsigned int prev = atomicAdd(done, 1u);
    *lastFlag = (prev == (unsigned int)(NBLK - 1)) ? 1 : 0;
  }
  __syncthreads();
  if (!*lastFlag) return;
  __threadfence();

  float* wc1s = (float*)smem;                   // 64 KB  [0, 65536)
  float* sgq  = (float*)(smem + 65536);         // 4x128  [65536, 67584)
  float* shq  = (float*)(smem + 67584);         // 4x128  [67584, 69632)
  float* wc2s = (float*)(smem + 69632);         // 128x10 [69632, 74752)
  float* bc1s = (float*)(smem + 74752);         // 128    [74752, 75264)
  float* bc2s = (float*)(smem + 75264);         // 10
  float* cshare = (float*)(smem + 75392);       // 4
  for (int i = tid; i < HID * HID; i += TPB) wc1s[i] = Wc1[i];
  for (int i = tid; i < HID * NC; i += TPB) wc2s[i] = Wc2[i];
  if (tid < HID) bc1s[tid] = bc1[tid];
  if (tid < NC) bc2s[tid] = bc2[tid];
  __syncthreads();

  const int q = tid >> 7;        // graph sub-group 0..3
  const int tq = tid & 127;
  for (int gi = 0; gi < NG / 4; ++gi) {
    const int g = gi * 4 + q;
    if (tq == 0) {
      float c = atomicAdd(&counts[g], 0.f);     // coherent (device-scope) read
      cshare[q] = c > 1.f ? c : 1.f;
    }
    float sv = atomicAdd(&sums[g * HID + tq], 0.f);
    __syncthreads();
    sgq[q * HID + tq] = sv / cshare[q];
    __syncthreads();
    float a = bc1s[tq];
    #pragma unroll 8
    for (int k = 0; k < HID; ++k) a += sgq[q * HID + k] * wc1s[k * HID + tq];
    shq[q * HID + tq] = a > 0.f ? a : 0.f;
    __syncthreads();
    if (tq < NC) {
      float o = bc2s[tq];
      #pragma unroll 8
      for (int h2 = 0; h2 < HID; ++h2) o += shq[q * HID + h2] * wc2s[h2 * NC + tq];
      out[g * NC + tq] = o;
    }
    __syncthreads();
  }
}

extern "C" void kernel_launch(void* const* d_in, const int* in_sizes, int n_in,
                              void* d_out, int out_size, void* d_ws, size_t ws_size,
                              hipStream_t stream) {
  const float* edge_attr = (const float*)d_in[0];
  const float* W1 = (const float*)d_in[1];
  const float* b1 = (const float*)d_in[2];
  const float* W2 = (const float*)d_in[3];
  const float* b2 = (const float*)d_in[4];
  const float* W3 = (const float*)d_in[5];
  const float* b3 = (const float*)d_in[6];
  const float* Wc1 = (const float*)d_in[7];
  const float* bc1 = (const float*)d_in[8];
  const float* Wc2 = (const float*)d_in[9];
  const float* bc2 = (const float*)d_in[10];
  const int* ei = (const int*)d_in[11];
  const int* batch = (const int*)d_in[12];

  const int E = in_sizes[0] / EDIM;
  const int N = in_sizes[12];
  const int* dst = ei + E;

  char* ws = (char*)d_ws;
  float* node_f = (float*)ws;                                       // N*128 f32
  float* sums = (float*)(ws + (size_t)N * HID * 4);                 // 128*128 f32
  float* counts = sums + NG * HID;                                  // 128 f32
  float* hself_f = counts + NG;                                     // 128 f32
  unsigned short* wt1 = (unsigned short*)(hself_f + HID);           // 8192 bf16
  unsigned short* wt2 = wt1 + 8192;                                 // 16384 bf16
  unsigned short* wt3 = wt2 + 16384;                                // 16384 bf16
  unsigned int* cnt = (unsigned int*)(wt3 + 16384);                 // N u32 (-> row_ptr)
  unsigned int* part = cnt + N;                                     // scan partials (<=256)
  int2* epd = (int2*)(part + 256);                                  // E int2 {edge, dst}
  unsigned int* cursor = (unsigned int*)(epd + E);                  // N u32
  unsigned int* wstart = cursor + N;                                // NWAVES+1 u32
  unsigned int* wnode = wstart + (NWAVES + 1);                      // NWAVES+1 u32
  unsigned int* done = wnode + (NWAVES + 1);                        // 1 u32

  const int SUMN = NG * HID + NG;
  const int zbc = (N + 1023) / 1024;
  const int zbs = (SUMN + 1023) / 1024;
  setup1_kernel<<<160 + zbc + zbs + 1, 256, 0, stream>>>(W1, W2, W3, b1, b2, b3, wt1, wt2, wt3,
                                                         cnt, sums, hself_f, N, zbc, zbs, SUMN);

  hist_kernel<<<(E + 1023) / 1024, 256, 0, stream>>>(dst, cnt, done, E);

  const int P = (N + 1023) / 1024;
  scan1_kernel<<<P, 256, 0, stream>>>(cnt, part, N);
  scan23_kernel<<<(N + 255) / 256, 256, 0, stream>>>(cnt, part, cursor, N);

  const int fillB = (E + 1023) / 1024;
  const int rangeB = (NWAVES + 1 + 255) / 256;
  fillrange_kernel<<<fillB + rangeB, 256, 0, stream>>>(dst, cursor, epd, cnt, wstart, wnode,
                                                       N, E, NWAVES, fillB);

  edge_kernel<<<NBLK, TPB, 0, stream>>>(edge_attr, epd, hself_f, wt1, wt2, wt3,
                                        node_f, wstart, wnode, batch, cnt,
                                        sums, counts, Wc1, bc1, Wc2, bc2,
                                        (float*)d_out, done, N, E);
}

// Round 15
// 264.121 us; speedup vs baseline: 1.4508x; 1.4508x over previous
//
#include <hip/hip_runtime.h>
#include <stdint.h>

typedef float f32x4 __attribute__((ext_vector_type(4)));
typedef short s16x8 __attribute__((ext_vector_type(8)));

#define EDIM 64
#define HID 128
#define NG 128
#define NC 10
#define WPB 8             // waves per block
#define TPB (WPB * 64)    // 512 threads
#define NBLK 512          // edge kernel blocks (2/CU exactly)
#define NWAVES (NBLK * WPB)
#define NEG_INF -3.402823466e38f

static __device__ __forceinline__ unsigned short f2bf(float x) {
  unsigned int u = __float_as_uint(x);
  u += 0x7FFFu + ((u >> 16) & 1u);   // round-to-nearest-even
  return (unsigned short)(u >> 16);
}
static __device__ __forceinline__ unsigned int cvtpk(float lo, float hi) {
  unsigned int r;
  asm("v_cvt_pk_bf16_f32 %0, %1, %2" : "=v"(r) : "v"(lo), "v"(hi));
  return r;
}
static __device__ __forceinline__ s16x8 mk8(unsigned int a, unsigned int b,
                                            unsigned int c, unsigned int d) {
  union { unsigned int u[4]; s16x8 v; } x;
  x.u[0] = a; x.u[1] = b; x.u[2] = c; x.u[3] = d;
  return x.v;
}
// K-position permutation: p[6:5]|p[4:3]|p[2:0] -> u = p[6:5]|p[2]|p[4:3]|p[1:0]
static __device__ __forceinline__ int sigma(int p) {
  return (p & 0x60) | ((p & 4) << 2) | ((p >> 1) & 0xC) | (p & 3);
}

// ---------------- setup1: pack weights + zero cnt + zero sums + h_self ----------------
__global__ void setup1_kernel(const float* __restrict__ W1, const float* __restrict__ W2,
                              const float* __restrict__ W3, const float* __restrict__ b1,
                              const float* __restrict__ b2, const float* __restrict__ b3,
                              unsigned short* __restrict__ wt1, unsigned short* __restrict__ wt2,
                              unsigned short* __restrict__ wt3, unsigned int* __restrict__ cnt,
                              float* __restrict__ pool0, float* __restrict__ hself_f,
                              int N, int zbc, int zbs, int SUMN) {
  __shared__ float s1[HID], s2[HID];
  const int b = blockIdx.x, t = threadIdx.x;
  if (b < 160) {                               // pack 40960 elements
    int gid = b * 256 + t;
    if (gid < 8192) {                          // W1: K=64 natural, N=128
      int k = gid >> 7, n = gid & 127;
      int off = (n * 128 + k * 2) ^ ((n & 7) << 4);
      *(unsigned short*)((char*)wt1 + off) = f2bf(W1[k * 128 + n]);
    } else if (gid < 24576) {                  // W2: K=128 sigma-permuted
      int idx = gid - 8192; int kp = idx >> 7, n = idx & 127;
      int off = (n * 256 + kp * 2) ^ ((n & 7) << 4);
      *(unsigned short*)((char*)wt2 + off) = f2bf(W2[sigma(kp) * 128 + n]);
    } else {                                   // W3: K=128 sigma-permuted
      int idx = gid - 24576; int kp = idx >> 7, n = idx & 127;
      int off = (n * 256 + kp * 2) ^ ((n & 7) << 4);
      *(unsigned short*)((char*)wt3 + off) = f2bf(W3[sigma(kp) * 128 + n]);
    }
  } else if (b < 160 + zbc) {                  // zero histogram, uint4
    int i4 = ((b - 160) * 256 + t) * 4;
    if (i4 + 3 < N) {
      uint4 z; z.x = z.y = z.z = z.w = 0u;
      *(uint4*)(cnt + i4) = z;
    } else {
      for (int j = 0; j < 4; ++j) if (i4 + j < N) cnt[i4 + j] = 0u;
    }
  } else if (b < 160 + zbc + zbs) {            // zero pool sums/counts, float4
    int i4 = ((b - 160 - zbc) * 256 + t) * 4;
    if (i4 + 3 < SUMN) {
      float4 z; z.x = z.y = z.z = z.w = 0.f;
      *(float4*)(pool0 + i4) = z;
    } else {
      for (int j = 0; j < 4; ++j) if (i4 + j < SUMN) pool0[i4 + j] = 0.f;
    }
  } else {                                     // h_self = MLP(0), f32 exact
    float h1 = 0.f, h2 = 0.f;
    if (t < HID) { h1 = b1[t]; h1 = h1 > 0.f ? h1 : 0.f; s1[t] = h1; }
    __syncthreads();
    if (t < HID) {
      h2 = b2[t];
      for (int k = 0; k < HID; ++k) h2 += s1[k] * W2[k * HID + t];
      h2 = h2 > 0.f ? h2 : 0.f; s2[t] = h2;
    }
    __syncthreads();
    if (t < HID) {
      float h3 = b3[t];
      for (int k = 0; k < HID; ++k) h3 += s2[k] * W3[k * HID + t];
      hself_f[t] = h3;
    }
  }
}

// ---------------- histogram (int4, 4 edges/thread) ----------------
__global__ void hist_kernel(const int* __restrict__ dst, unsigned int* __restrict__ cnt, int E) {
  int i4 = (blockIdx.x * 256 + threadIdx.x) * 4;
  if (i4 + 3 < E) {
    int4 d4 = *(const int4*)(dst + i4);
    atomicAdd(&cnt[d4.x], 1u); atomicAdd(&cnt[d4.y], 1u);
    atomicAdd(&cnt[d4.z], 1u); atomicAdd(&cnt[d4.w], 1u);
  } else {
    for (int j = 0; j < 4; ++j) if (i4 + j < E) atomicAdd(&cnt[dst[i4 + j]], 1u);
  }
}

// ---------------- scan phase 1: intra-block exclusive + raw block totals ----------------
__global__ void scan1_kernel(unsigned int* __restrict__ cnt, unsigned int* __restrict__ part,
                             int N) {
  __shared__ unsigned int sh[256];
  const int t = threadIdx.x;
  const int base = blockIdx.x * 1024 + t * 4;
  unsigned int v[4]; unsigned int s = 0;
  #pragma unroll
  for (int j = 0; j < 4; ++j) { v[j] = (base + j < N) ? cnt[base + j] : 0u; s += v[j]; }
  sh[t] = s; __syncthreads();
  for (int off = 1; off < 256; off <<= 1) {
    unsigned int x = (t >= off) ? sh[t - off] : 0u;
    __syncthreads();
    sh[t] += x;
    __syncthreads();
  }
  if (t == 255) part[blockIdx.x] = sh[255];
  unsigned int excl = (t == 0) ? 0u : sh[t - 1];
  #pragma unroll
  for (int j = 0; j < 4; ++j) {
    if (base + j < N) { unsigned int old = v[j]; cnt[base + j] = excl; excl += old; }
  }
}

// ---------------- scan phases 2+3 merged: each block reduces preceding partials ----------------
__global__ void scan23_kernel(unsigned int* __restrict__ cnt, const unsigned int* __restrict__ part,
                              unsigned int* __restrict__ cursor, int N) {
  __shared__ unsigned int red[256];
  const int t = threadIdx.x;
  const int chunk = blockIdx.x >> 2;             // 4 blocks of 256 per 1024-chunk
  red[t] = (t < chunk) ? part[t] : 0u;
  __syncthreads();
  for (int off = 128; off > 0; off >>= 1) {
    if (t < off) red[t] += red[t + off];
    __syncthreads();
  }
  const unsigned int offv = red[0];
  int i = blockIdx.x * 256 + t;
  if (i < N) {
    unsigned int v = cnt[i] + offv;
    cnt[i] = v;          // row_ptr (preserved)
    cursor[i] = v;       // mutable copy for fill
  }
}

// ---------------- fill (int4 -> int2 epd) + per-wave node-aligned ranges (+wnode) ----------------
__global__ void fillrange_kernel(const int* __restrict__ dst, unsigned int* __restrict__ cursor,
                                 int2* __restrict__ epd, const unsigned int* __restrict__ row_ptr,
                                 unsigned int* __restrict__ wstart, unsigned int* __restrict__ wnode,
                                 int N, int E, int W, int fillB) {
  const int b = blockIdx.x, t = threadIdx.x;
  if (b < fillB) {
    int i4 = (b * 256 + t) * 4;
    if (i4 + 3 < E) {
      int4 d4 = *(const int4*)(dst + i4);
      unsigned int p0 = atomicAdd(&cursor[d4.x], 1u); epd[p0] = make_int2(i4 + 0, d4.x);
      unsigned int p1 = atomicAdd(&cursor[d4.y], 1u); epd[p1] = make_int2(i4 + 1, d4.y);
      unsigned int p2 = atomicAdd(&cursor[d4.z], 1u); epd[p2] = make_int2(i4 + 2, d4.z);
      unsigned int p3 = atomicAdd(&cursor[d4.w], 1u); epd[p3] = make_int2(i4 + 3, d4.w);
    } else {
      for (int j = 0; j < 4; ++j)
        if (i4 + j < E) {
          int d = dst[i4 + j];
          unsigned int p = atomicAdd(&cursor[d], 1u);
          epd[p] = make_int2(i4 + j, d);
        }
    }
  } else {
    int w = (b - fillB) * 256 + t;
    if (w > W) return;
    unsigned int target = (unsigned int)(((unsigned long long)w * (unsigned long long)E) /
                                         (unsigned long long)W);
    int lo = 0, hi = N;
    while (lo < hi) {
      int mid = (lo + hi) >> 1;
      if (row_ptr[mid] >= target) hi = mid; else lo = mid + 1;
    }
    wnode[w] = (unsigned int)lo;
    wstart[w] = (lo < N) ? row_ptr[lo] : (unsigned int)E;
  }
}

// ---------------- fused edge MLP + exclusive segmented-max + POOL TAIL ----------------
// Core verified R8-R13. Waves own node-aligned edge ranges -> plain stores.
// Pool tail: wave exclusively owns nodes [wnode[gw], wnode[gw+1)) (finalized
// by itself) -> accumulates graph-mean sums directly; pool_kernel eliminated.
__global__ __launch_bounds__(TPB, 2) void edge_kernel(
    const float* __restrict__ edge_attr, const int2* __restrict__ epd,
    const float* __restrict__ hself_f,
    const unsigned short* __restrict__ wt1, const unsigned short* __restrict__ wt2,
    const unsigned short* __restrict__ wt3, float* __restrict__ node_f,
    const unsigned int* __restrict__ wstart, const unsigned int* __restrict__ wnode,
    const int* __restrict__ batch, const unsigned int* __restrict__ row_ptr,
    float* __restrict__ sums, float* __restrict__ counts, int N, int E) {
  __shared__ __align__(16) unsigned short Wb1[8192];      // 16 KB
  __shared__ __align__(16) unsigned short Wb2[16384];     // 32 KB
  __shared__ __align__(16) unsigned short Wb3[16384];     // 32 KB  (total 80 KB)

  const int tid = threadIdx.x;
  { // stage all three weight matrices once
    const uint4* s1 = (const uint4*)wt1; uint4* d1 = (uint4*)Wb1;
    #pragma unroll
    for (int i = 0; i < 2; ++i) d1[tid + i * TPB] = s1[tid + i * TPB];
    const uint4* s2 = (const uint4*)wt2; uint4* d2 = (uint4*)Wb2;
    #pragma unroll
    for (int i = 0; i < 4; ++i) d2[tid + i * TPB] = s2[tid + i * TPB];
    const uint4* s3 = (const uint4*)wt3; uint4* d3 = (uint4*)Wb3;
    #pragma unroll
    for (int i = 0; i < 4; ++i) d3[tid + i * TPB] = s3[tid + i * TPB];
  }
  __syncthreads();   // the only barrier

  const int w = tid >> 6;
  const int l = tid & 63;
  const int hi = l >> 4;         // lane quarter 0..3
  const int lm = l & 15;         // 0..15

  const int gw = blockIdx.x * WPB + w;
  const int s = (int)wstart[gw];
  const int e = (int)wstart[gw + 1];

  if (s < e) {
    float hs[8];
    #pragma unroll
    for (int nf = 0; nf < 8; ++nf) hs[nf] = hself_f[nf * 16 + lm];

    int pd = -1;   // previous subtile's last dst (wave-uniform)

    // ---- prologue: gather+convert tile s; peN = perm ids for s+32 ----
    s16x8 a1[2][2];
    int peN[2];
    {
      int pe[2];
      #pragma unroll
      for (int m = 0; m < 2; ++m) {
        int er = s + m * 16 + lm; if (er >= e) er = e - 1;
        pe[m] = epd[er].x;
      }
      f32x4 raw[8];
      #pragma unroll
      for (int m = 0; m < 2; ++m) {
        const float* ap = edge_attr + (size_t)pe[m] * EDIM + hi * 8;
        #pragma unroll
        for (int kf = 0; kf < 2; ++kf) {
          raw[m * 4 + kf * 2 + 0] = __builtin_nontemporal_load((const f32x4*)(ap + kf * 32));
          raw[m * 4 + kf * 2 + 1] = __builtin_nontemporal_load((const f32x4*)(ap + kf * 32 + 4));
        }
      }
      #pragma unroll
      for (int m = 0; m < 2; ++m) {
        int er = s + 32 + m * 16 + lm; if (er >= e) er = e - 1;
        peN[m] = epd[er].x;
      }
      #pragma unroll
      for (int m = 0; m < 2; ++m)
        #pragma unroll
        for (int kf = 0; kf < 2; ++kf) {
          f32x4 x0 = raw[m * 4 + kf * 2 + 0];
          f32x4 x1 = raw[m * 4 + kf * 2 + 1];
          a1[m][kf] = mk8(cvtpk(x0[0], x0[1]), cvtpk(x0[2], x0[3]),
                          cvtpk(x1[0], x1[1]), cvtpk(x1[2], x1[3]));
        }
    }

    for (int t = s; t < e; t += 32) {
      f32x4 acc[2][8];
      #pragma unroll
      for (int m = 0; m < 2; ++m)
        #pragma unroll
        for (int nf = 0; nf < 8; ++nf) acc[m][nf] = (f32x4){0.f, 0.f, 0.f, 0.f};

      // ---- layer 1 (transposed): h1^T = W1^T · X^T  (a1 dies here) ----
      #pragma unroll
      for (int kf = 0; kf < 2; ++kf) {
        #pragma unroll
        for (int nf = 0; nf < 8; ++nf) {
          int n = nf * 16 + lm;
          int off = (n * 128 + kf * 64 + hi * 16) ^ ((n & 7) << 4);
          s16x8 wf = *(const s16x8*)((const char*)Wb1 + off);
          acc[0][nf] = __builtin_amdgcn_mfma_f32_16x16x32_bf16(wf, a1[0][kf], acc[0][nf], 0, 0, 0);
          acc[1][nf] = __builtin_amdgcn_mfma_f32_16x16x32_bf16(wf, a1[1][kf], acc[1][nf], 0, 0, 0);
        }
      }

      // ---- issue NEXT tile gather m=0 ----
      f32x4 rawA[4];
      {
        const float* ap = edge_attr + (size_t)peN[0] * EDIM + hi * 8;
        rawA[0] = __builtin_nontemporal_load((const f32x4*)(ap));
        rawA[1] = __builtin_nontemporal_load((const f32x4*)(ap + 4));
        rawA[2] = __builtin_nontemporal_load((const f32x4*)(ap + 32));
        rawA[3] = __builtin_nontemporal_load((const f32x4*)(ap + 36));
      }

      // ---- boundary 1: relu + pack in-register ----
      unsigned int pk1[2][8][2];
      #pragma unroll
      for (int m = 0; m < 2; ++m)
        #pragma unroll
        for (int nf = 0; nf < 8; ++nf) {
          float v0 = fmaxf(acc[m][nf][0], 0.f), v1 = fmaxf(acc[m][nf][1], 0.f);
          float v2 = fmaxf(acc[m][nf][2], 0.f), v3 = fmaxf(acc[m][nf][3], 0.f);
          pk1[m][nf][0] = cvtpk(v0, v1);
          pk1[m][nf][1] = cvtpk(v2, v3);
        }

      // ---- layer 2 (transposed): h2^T = W2p^T · h1^T ----
      #pragma unroll
      for (int m = 0; m < 2; ++m)
        #pragma unroll
        for (int nf = 0; nf < 8; ++nf) acc[m][nf] = (f32x4){0.f, 0.f, 0.f, 0.f};
      #pragma unroll
      for (int kf = 0; kf < 4; ++kf) {
        s16x8 b0 = mk8(pk1[0][2 * kf][0], pk1[0][2 * kf][1],
                       pk1[0][2 * kf + 1][0], pk1[0][2 * kf + 1][1]);
        s16x8 b1f = mk8(pk1[1][2 * kf][0], pk1[1][2 * kf][1],
                        pk1[1][2 * kf + 1][0], pk1[1][2 * kf + 1][1]);
        #pragma unroll
        for (int nf = 0; nf < 8; ++nf) {
          int n = nf * 16 + lm;
          int off = (n * 256 + kf * 64 + hi * 16) ^ ((n & 7) << 4);
          s16x8 wf = *(const s16x8*)((const char*)Wb2 + off);
          acc[0][nf] = __builtin_amdgcn_mfma_f32_16x16x32_bf16(wf, b0, acc[0][nf], 0, 0, 0);
          acc[1][nf] = __builtin_amdgcn_mfma_f32_16x16x32_bf16(wf, b1f, acc[1][nf], 0, 0, 0);
        }
      }

      // ---- convert rawA -> next a1[0]; issue gather m=1 ----
      a1[0][0] = mk8(cvtpk(rawA[0][0], rawA[0][1]), cvtpk(rawA[0][2], rawA[0][3]),
                     cvtpk(rawA[1][0], rawA[1][1]), cvtpk(rawA[1][2], rawA[1][3]));
      a1[0][1] = mk8(cvtpk(rawA[2][0], rawA[2][1]), cvtpk(rawA[2][2], rawA[2][3]),
                     cvtpk(rawA[3][0], rawA[3][1]), cvtpk(rawA[3][2], rawA[3][3]));
      f32x4 rawB[4];
      {
        const float* ap = edge_attr + (size_t)peN[1] * EDIM + hi * 8;
        rawB[0] = __builtin_nontemporal_load((const f32x4*)(ap));
        rawB[1] = __builtin_nontemporal_load((const f32x4*)(ap + 4));
        rawB[2] = __builtin_nontemporal_load((const f32x4*)(ap + 32));
        rawB[3] = __builtin_nontemporal_load((const f32x4*)(ap + 36));
      }

      // ---- boundary 2: relu + pack ----
      unsigned int pk2[2][8][2];
      #pragma unroll
      for (int m = 0; m < 2; ++m)
        #pragma unroll
        for (int nf = 0; nf < 8; ++nf) {
          float v0 = fmaxf(acc[m][nf][0], 0.f), v1 = fmaxf(acc[m][nf][1], 0.f);
          float v2 = fmaxf(acc[m][nf][2], 0.f), v3 = fmaxf(acc[m][nf][3], 0.f);
          pk2[m][nf][0] = cvtpk(v0, v1);
          pk2[m][nf][1] = cvtpk(v2, v3);
        }

      // ---- layer 3 (normal): h3 = h2 · W3p ----
      #pragma unroll
      for (int m = 0; m < 2; ++m)
        #pragma unroll
        for (int nf = 0; nf < 8; ++nf) acc[m][nf] = (f32x4){0.f, 0.f, 0.f, 0.f};
      #pragma unroll
      for (int kf = 0; kf < 4; ++kf) {
        s16x8 af0 = mk8(pk2[0][2 * kf][0], pk2[0][2 * kf][1],
                        pk2[0][2 * kf + 1][0], pk2[0][2 * kf + 1][1]);
        s16x8 af1 = mk8(pk2[1][2 * kf][0], pk2[1][2 * kf][1],
                        pk2[1][2 * kf + 1][0], pk2[1][2 * kf + 1][1]);
        #pragma unroll
        for (int nf = 0; nf < 8; ++nf) {
          int n = nf * 16 + lm;
          int off = (n * 256 + kf * 64 + hi * 16) ^ ((n & 7) << 4);
          s16x8 wf = *(const s16x8*)((const char*)Wb3 + off);
          acc[0][nf] = __builtin_amdgcn_mfma_f32_16x16x32_bf16(af0, wf, acc[0][nf], 0, 0, 0);
          acc[1][nf] = __builtin_amdgcn_mfma_f32_16x16x32_bf16(af1, wf, acc[1][nf], 0, 0, 0);
        }
      }

      // ---- convert rawB -> next a1[1]; prefetch perm ids for t+64 ----
      a1[1][0] = mk8(cvtpk(rawB[0][0], rawB[0][1]), cvtpk(rawB[0][2], rawB[0][3]),
                     cvtpk(rawB[1][0], rawB[1][1]), cvtpk(rawB[1][2], rawB[1][3]));
      a1[1][1] = mk8(cvtpk(rawB[2][0], rawB[2][1]), cvtpk(rawB[2][2], rawB[2][3]),
                     cvtpk(rawB[3][0], rawB[3][1]), cvtpk(rawB[3][2], rawB[3][3]));
      int peN2[2];
      #pragma unroll
      for (int m = 0; m < 2; ++m) {
        int er = t + 64 + m * 16 + lm; if (er >= e) er = e - 1;
        peN2[m] = epd[er].x;
      }

      // ---- epilogue: dst ids + exclusive segmented max (f32 stores) ----
      int dd[2][4];
      #pragma unroll
      for (int m = 0; m < 2; ++m)
        #pragma unroll
        for (int i = 0; i < 4; ++i) {
          int e2 = t + m * 16 + hi * 4 + i;
          dd[m][i] = (e2 < e) ? epd[e2].y : -1;
        }

      #pragma unroll
      for (int m = 0; m < 2; ++m) {
        const int d0 = dd[m][0], d1 = dd[m][1], d2 = dd[m][2], d3 = dd[m][3];
        const bool q01 = (d0 == d1), q12 = (d1 == d2), q23 = (d2 == d3);
        const int dt = d3, dh = d0;
        const int uni = (d0 == d3);
        const int dh1 = __shfl_down(dh, 16), dh2 = __shfl_down(dh, 32), dh3 = __shfl_down(dh, 48);
        const int un1 = __shfl_down(uni, 16), un2 = __shfl_down(uni, 32);
        const int dtprev = __shfl_up(dt, 16);
        const bool c1 = (hi < 3) && (dh1 == dt);
        const bool c2 = c1 && un1 && (dh2 == dh1);
        const bool c3 = c2 && un2 && (dh3 == dh2);
        const bool h0 = (hi == 0) || (dtprev != d0);
        const bool h1 = !q01, h2 = !q12, h3 = !q23;
        const int d_last = __shfl(d3, 48);

        const bool cont = (hi == 0) && (d0 >= 0) && (d0 == pd);
        float prevv[8];
        if (cont) {
          #pragma unroll
          for (int nf = 0; nf < 8; ++nf)
            prevv[nf] = node_f[(size_t)d0 * HID + nf * 16 + lm];
        }

        #pragma unroll
        for (int nf = 0; nf < 8; ++nf) {
          float v0 = acc[m][nf][0], v1 = acc[m][nf][1], v2 = acc[m][nf][2], v3 = acc[m][nf][3];
          float s3 = v3;
          float s2 = q23 ? fmaxf(v2, s3) : v2;
          float s1 = q12 ? fmaxf(v1, s2) : v1;
          float s0 = q01 ? fmaxf(v0, s1) : v0;
          float S1 = __shfl_down(s0, 16), S2 = __shfl_down(s0, 32), S3 = __shfl_down(s0, 48);
          float X = NEG_INF;
          X = c1 ? S1 : X;
          X = c2 ? fmaxf(X, S2) : X;
          X = c3 ? fmaxf(X, S3) : X;
          const float f0 = (d0 == dt) ? fmaxf(s0, X) : s0;
          const float f1 = (d1 == dt) ? fmaxf(s1, X) : s1;
          const float f2 = (d2 == dt) ? fmaxf(s2, X) : s2;
          const float f3 = fmaxf(s3, X);
          const int col = nf * 16 + lm;
          if (h0 && d0 >= 0) {
            float u = fmaxf(f0, hs[nf]);
            if (cont) u = fmaxf(u, prevv[nf]);
            node_f[(size_t)d0 * HID + col] = u;
          }
          if (h1 && d1 >= 0) node_f[(size_t)d1 * HID + col] = fmaxf(f1, hs[nf]);
          if (h2 && d2 >= 0) node_f[(size_t)d2 * HID + col] = fmaxf(f2, hs[nf]);
          if (h3 && d3 >= 0) node_f[(size_t)d3 * HID + col] = fmaxf(f3, hs[nf]);
        }
        pd = d_last;
      }

      peN[0] = peN2[0]; peN[1] = peN2[1];
    }
  }

  // ---- POOL TAIL: this wave exclusively owns nodes [wnode[gw], wnode[gw+1]) ----
  {
    int n0 = (int)wnode[gw];
    int n1 = (gw == NWAVES - 1) ? N : (int)wnode[gw + 1];
    if (n1 > N) n1 = N;
    if (n0 < n1) {
      const int c0 = l * 2;   // each lane accumulates 2 features
      const float hsa = hself_f[c0], hsb = hself_f[c0 + 1];
      float sum0 = 0.f, sum1 = 0.f;
      int segn = 0;
      int cur = batch[n0];
      for (int n = n0; n < n1; ++n) {
        int g = batch[n];
        if (g != cur) {
          atomicAdd(&sums[cur * HID + c0], sum0);
          atomicAdd(&sums[cur * HID + c0 + 1], sum1);
          if (l == 0) atomicAdd(&counts[cur], (float)segn);
          sum0 = sum1 = 0.f; segn = 0; cur = g;
        }
        unsigned int rs = row_ptr[n];
        unsigned int re = (n + 1 < N) ? row_ptr[n + 1] : (unsigned int)E;
        if (re > rs) {
          sum0 += node_f[(size_t)n * HID + c0];
          sum1 += node_f[(size_t)n * HID + c0 + 1];
        } else {
          sum0 += hsa; sum1 += hsb;
        }
        segn++;
      }
      atomicAdd(&sums[cur * HID + c0], sum0);
      atomicAdd(&sums[cur * HID + c0 + 1], sum1);
      if (l == 0) atomicAdd(&counts[cur], (float)segn);
    }
  }
}

// ---------------- classifier ----------------
__global__ void cls_kernel(const float* __restrict__ sums, const float* __restrict__ counts,
                           const float* __restrict__ Wc1, const float* __restrict__ bc1,
                           const float* __restrict__ Wc2, const float* __restrict__ bc2,
                           float* __restrict__ out) {
  __shared__ float sg[HID], sh[HID];
  int g = blockIdx.x, t = threadIdx.x;  // 128 threads
  float c = counts[g]; c = c > 1.f ? c : 1.f;
  sg[t] = sums[g * HID + t] / c;
  __syncthreads();
  float a = bc1[t];
  #pragma unroll 8
  for (int k = 0; k < HID; ++k) a += sg[k] * Wc1[k * HID + t];
  sh[t] = a > 0.f ? a : 0.f;
  __syncthreads();
  if (t < NC) {
    float o = bc2[t];
    #pragma unroll 8
    for (int h = 0; h < HID; ++h) o += sh[h] * Wc2[h * NC + t];
    out[g * NC + t] = o;
  }
}

extern "C" void kernel_launch(void* const* d_in, const int* in_sizes, int n_in,
                              void* d_out, int out_size, void* d_ws, size_t ws_size,
                              hipStream_t stream) {
  const float* edge_attr = (const float*)d_in[0];
  const float* W1 = (const float*)d_in[1];
  const float* b1 = (const float*)d_in[2];
  const float* W2 = (const float*)d_in[3];
  const float* b2 = (const float*)d_in[4];
  const float* W3 = (const float*)d_in[5];
  const float* b3 = (const float*)d_in[6];
  const float* Wc1 = (const float*)d_in[7];
  const float* bc1 = (const float*)d_in[8];
  const float* Wc2 = (const float*)d_in[9];
  const float* bc2 = (const float*)d_in[10];
  const int* ei = (const int*)d_in[11];
  const int* batch = (const int*)d_in[12];

  const int E = in_sizes[0] / EDIM;
  const int N = in_sizes[12];
  const int* dst = ei + E;

  char* ws = (char*)d_ws;
  float* node_f = (float*)ws;                                       // N*128 f32
  float* sums = (float*)(ws + (size_t)N * HID * 4);                 // 128*128 f32
  float* counts = sums + NG * HID;                                  // 128 f32
  float* hself_f = counts + NG;                                     // 128 f32
  unsigned short* wt1 = (unsigned short*)(hself_f + HID);           // 8192 bf16
  unsigned short* wt2 = wt1 + 8192;                                 // 16384 bf16
  unsigned short* wt3 = wt2 + 16384;                                // 16384 bf16
  unsigned int* cnt = (unsigned int*)(wt3 + 16384);                 // N u32 (-> row_ptr)
  unsigned int* part = cnt + N;                                     // scan partials (<=256)
  int2* epd = (int2*)(part + 256);                                  // E int2 {edge, dst}
  unsigned int* cursor = (unsigned int*)(epd + E);                  // N u32
  unsigned int* wstart = cursor + N;                                // NWAVES+1 u32
  unsigned int* wnode = wstart + (NWAVES + 1);                      // NWAVES+1 u32

  const int SUMN = NG * HID + NG;
  const int zbc = (N + 1023) / 1024;
  const int zbs = (SUMN + 1023) / 1024;
  setup1_kernel<<<160 + zbc + zbs + 1, 256, 0, stream>>>(W1, W2, W3, b1, b2, b3, wt1, wt2, wt3,
                                                         cnt, sums, hself_f, N, zbc, zbs, SUMN);

  hist_kernel<<<(E + 1023) / 1024, 256, 0, stream>>>(dst, cnt, E);

  const int P = (N + 1023) / 1024;
  scan1_kernel<<<P, 256, 0, stream>>>(cnt, part, N);
  scan23_kernel<<<(N + 255) / 256, 256, 0, stream>>>(cnt, part, cursor, N);

  const int fillB = (E + 1023) / 1024;
  const int rangeB = (NWAVES + 1 + 255) / 256;
  fillrange_kernel<<<fillB + rangeB, 256, 0, stream>>>(dst, cursor, epd, cnt, wstart, wnode,
                                                       N, E, NWAVES, fillB);

  edge_kernel<<<NBLK, TPB, 0, stream>>>(edge_attr, epd, hself_f, wt1, wt2, wt3,
                                        node_f, wstart, wnode, batch, cnt,
                                        sums, counts, N, E);

  cls_kernel<<<NG, 128, 0, stream>>>(sums, counts, Wc1, bc1, Wc2, bc2, (float*)d_out);
}